// Round 8
// baseline (850.172 us; speedup 1.0000x reference)
//
#include <hip/hip_runtime.h>

// ---------------------------------------------------------------------------
// RNN_83313775608289: 4-layer tanh RNN (H=64) + FC, B=512, T=1024, D_in=52.
// SINGLE fused kernel (r8): 5-wave SELF-CONTAINED pipeline. r7's 8-wave
// producer/consumer split was issue-volume-bound (455 instr/wave/interval vs
// 128 dot2 payload; VALUBusy 66%). Now each layer wave computes BOTH its
// input GEMV (4 independent 64-wide GEMVs/interval, P stays in registers --
// the P LDS handoff is gone) and its serial recurrent chain:
//     wave 0: pre[kk]  (Wih0 x, 28-pair) + h0 chain        kk = k-0
//     wave 1: P1 = Wih1 h0[kk]           + h1 chain        kk = k-1
//     wave 2: P2 = Wih2 h1[kk]           + h2 chain        kk = k-2
//     wave 3: P3 = Wih3 h2[kk]           + h3 chain        kk = k-3
//     wave 4: FC = Wfc h3[kk] + bfc -> out; x-tile staging kk = k-4
//   One block (5 waves, 320 thr) per batch row; 512 blocks = 2/CU
//   (10 waves/CU). 4 time steps per barrier interval, 260 intervals.
//   Slot discipline keyed on WINDOW parity kk&1:
//     h: wave L writes hbuf[L][kk&1]; consumer wave L+1 reads window kk at
//        slot kk&1 one interval later; concurrent writer is at (kk+1)&1. ✓
//     x: wave 4 at interval k stages window k+1 into pxs[(k+1)&1]; wave 0
//        reads window k from pxs[k&1]. xr regs loaded 1 interval ahead. ✓
//   Weights per wave: Wih_L + Whh_L = 64 h2 VGPRs (wave 4: Wfc only).
//   __launch_bounds__(320,4) caps VGPR at 128 -- no spill (r5 lesson;
//   verify WRITE_SIZE stays ~132096 KB).
// ---------------------------------------------------------------------------

typedef __fp16 h2 __attribute__((ext_vector_type(2)));

__device__ __forceinline__ h2 pk2(float a, float b) {
#if __has_builtin(__builtin_amdgcn_cvt_pkrtz)
  return __builtin_amdgcn_cvt_pkrtz(a, b);
#else
  h2 r; r.x = (__fp16)a; r.y = (__fp16)b; return r;
#endif
}

__device__ __forceinline__ float fdot2f(h2 a, h2 b, float c) {
#if __has_builtin(__builtin_amdgcn_fdot2)
  return __builtin_amdgcn_fdot2(a, b, c, false);
#else
  return c + (float)a.x * (float)b.x + (float)a.y * (float)b.y;
#endif
}

__device__ __forceinline__ h2 bc(unsigned int u) {
  return __builtin_bit_cast(h2, u);
}

__device__ __forceinline__ unsigned int ubc(h2 v) {
  return __builtin_bit_cast(unsigned int, v);
}

__device__ __forceinline__ float fast_tanh(float x) {
  float e = __expf(2.0f * x);          // overflow -> +inf -> result 1.0 (ok)
#if __has_builtin(__builtin_amdgcn_rcpf)
  return 1.0f - 2.0f * __builtin_amdgcn_rcpf(e + 1.0f);
#else
  return 1.0f - 2.0f / (e + 1.0f);
#endif
}

#define T_STEPS 1024

// 64-wide GEMV: 8 uniform ds_read_b128 + 32 dot2 in 4 chains. Macro so the
// weight array indices stay compile-time -> registers (no runtime indexing).
#define GEMV64(RES, HPTR, WARR, INIT)                         \
  do {                                                        \
    const uint4* hp_ = (const uint4*)(HPTR);                  \
    float a0_ = (INIT), a1_ = 0.f, a2_ = 0.f, a3_ = 0.f;      \
    _Pragma("unroll")                                         \
    for (int q_ = 0; q_ < 8; ++q_) {                          \
      uint4 u_ = hp_[q_];                                     \
      a0_ = fdot2f(bc(u_.x), WARR[4 * q_ + 0], a0_);          \
      a1_ = fdot2f(bc(u_.y), WARR[4 * q_ + 1], a1_);          \
      a2_ = fdot2f(bc(u_.z), WARR[4 * q_ + 2], a2_);          \
      a3_ = fdot2f(bc(u_.w), WARR[4 * q_ + 3], a3_);          \
    }                                                         \
    RES = (a0_ + a1_) + (a2_ + a3_);                          \
  } while (0)

// 28-pair pre GEMV (52 data + 2 zero-pad pairs; pads zero on BOTH sides so
// padded products are exactly 0): 7 uniform ds_read_b128 + 28 dot2, 4 chains.
#define PREGEMV(RES, XPTR, INIT)                              \
  do {                                                        \
    const uint4* xp_ = (const uint4*)(XPTR);                  \
    float a0_ = (INIT), a1_ = 0.f, a2_ = 0.f, a3_ = 0.f;      \
    _Pragma("unroll")                                         \
    for (int q_ = 0; q_ < 7; ++q_) {                          \
      uint4 u_ = xp_[q_];                                     \
      a0_ = fdot2f(bc(u_.x), wx_[4 * q_ + 0], a0_);           \
      a1_ = fdot2f(bc(u_.y), wx_[4 * q_ + 1], a1_);           \
      a2_ = fdot2f(bc(u_.z), wx_[4 * q_ + 2], a2_);           \
      a3_ = fdot2f(bc(u_.w), wx_[4 * q_ + 3], a3_);           \
    }                                                         \
    RES = (a0_ + a1_) + (a2_ + a3_);                          \
  } while (0)

__global__ __launch_bounds__(320, 4) void rnn_fused5(
    const float* __restrict__ x, const float* __restrict__ Wih0,
    const float* __restrict__ bih0, const float* __restrict__ bhh0,
    const float* __restrict__ Whh0, const float* __restrict__ Wih,
    const float* __restrict__ Whh, const float* __restrict__ bih,
    const float* __restrict__ bhh, const float* __restrict__ Wfc,
    const float* __restrict__ bfc, float* __restrict__ out) {
  const int tid  = threadIdx.x;
  const int lane = tid & 63;
  const int wv   = __builtin_amdgcn_readfirstlane(tid >> 6);  // scalar 0..4
  const int b    = blockIdx.x;

  // h handoff: [layer][window-parity][step][lane], f16
  __shared__ __attribute__((aligned(16))) __fp16 hbuf[4][2][4][64];   // 4 KiB
  // x-stage: [window-parity][step][32 f16-pairs] (26 data + 6 zero pad)
  __shared__ __attribute__((aligned(16))) unsigned int pxs[2][4][32]; // 1 KiB

  // zero-init hbuf (h[t=-1] = 0) and pxs (pads must be 0)
  for (int i = tid; i < 1024; i += 320) ((unsigned int*)hbuf)[i] = 0u;
  if (tid < 256) ((unsigned int*)pxs)[tid] = 0u;

  // recurrent (waves 0-3) or FC (wave 4) weights + per-step bias
  const float* Wr;
  float bias = 0.f;
  if (wv == 4) {
    Wr = Wfc; bias = bfc[lane];
  } else if (wv == 0) {
    Wr = Whh0;  // layer-0 bias folded into the pre GEMV init (preb)
  } else {
    Wr = Whh + (wv - 1) * 4096;
    bias = bih[(wv - 1) * 64 + lane] + bhh[(wv - 1) * 64 + lane];
  }

  h2 wr_[32];
  {
    const float2* s = (const float2*)(Wr + lane * 64);
#pragma unroll
    for (int q = 0; q < 32; ++q) { float2 v = s[q]; wr_[q] = pk2(v.x, v.y); }
  }

  // input weights: wave 0: Wih0 row (26 pairs + 2 zero); waves 1-3: Wih_L row
  h2 wx_[32];
  float preb = 0.f;
  if (wv == 0) {
    const float2* s = (const float2*)(Wih0 + lane * 52);
#pragma unroll
    for (int q = 0; q < 26; ++q) { float2 v = s[q]; wx_[q] = pk2(v.x, v.y); }
    wx_[26] = pk2(0.f, 0.f);
    wx_[27] = pk2(0.f, 0.f);
    preb = bih0[lane] + bhh0[lane];
  } else if (wv <= 3) {
    const float2* s = (const float2*)(Wih + (wv - 1) * 4096 + lane * 64);
#pragma unroll
    for (int q = 0; q < 32; ++q) { float2 v = s[q]; wx_[q] = pk2(v.x, v.y); }
  }

  // wave-4 x staging state
  float4 xr = {0.f, 0.f, 0.f, 0.f};  // window k+2 in flight
  const float4* xg = (const float4*)(x + (long)b * T_STEPS * 52);
  const int xrow = (lane / 13) & 3;   // step within window
  const int xcol = lane % 13;         // float4 index within row
  const bool xact = (lane < 52);      // 52 float4 per window

  __syncthreads();  // zero-init complete before wave 4 stages

  if (wv == 4 && xact) {
    // prologue: window 0 -> slot 0; window 1 -> regs
    float4 xa = xg[lane];
    xr = xg[52 + lane];
    pxs[0][xrow][2 * xcol]     = ubc(pk2(xa.x, xa.y));
    pxs[0][xrow][2 * xcol + 1] = ubc(pk2(xa.z, xa.w));
  }
  __syncthreads();

  float* op = out + (long)b * T_STEPS * 64 + lane;

#pragma unroll 1
  for (int k = 0; k < 256 + 4; ++k) {
    const unsigned kk = (unsigned)(k - wv);  // this wave's window
    if (kk < 256u) {
      const int rd = (int)((kk - 1) & 1u);   // prev-window slot
      const int wr = (int)(kk & 1u);         // this-window slot
      if (wv == 0) {
        // pre[t] = Wih0 x_t + (bih0+bhh0), 4 independent (in-register)
        float p0, p1, p2, p3;
        PREGEMV(p0, &pxs[wr][0][0], preb);
        PREGEMV(p1, &pxs[wr][1][0], preb);
        PREGEMV(p2, &pxs[wr][2][0], preb);
        PREGEMV(p3, &pxs[wr][3][0], preb);
        // serial chain: h0[t] = tanh(pre[t] + Whh0 h0[t-1])
        float hv;
        GEMV64(hv, hbuf[0][rd][3], wr_, 0.f);
        float h0v = fast_tanh(hv + p0); hbuf[0][wr][0][lane] = (__fp16)h0v;
        GEMV64(hv, hbuf[0][wr][0], wr_, 0.f);
        float h1v = fast_tanh(hv + p1); hbuf[0][wr][1][lane] = (__fp16)h1v;
        GEMV64(hv, hbuf[0][wr][1], wr_, 0.f);
        float h2v = fast_tanh(hv + p2); hbuf[0][wr][2][lane] = (__fp16)h2v;
        GEMV64(hv, hbuf[0][wr][2], wr_, 0.f);
        float h3v = fast_tanh(hv + p3); hbuf[0][wr][3][lane] = (__fp16)h3v;
      } else if (wv <= 3) {
        const int L = wv;
        // P_L[t] = Wih_L h_{L-1}[t], 4 independent (in-register)
        float p0, p1, p2, p3;
        GEMV64(p0, hbuf[L - 1][wr][0], wx_, 0.f);
        GEMV64(p1, hbuf[L - 1][wr][1], wx_, 0.f);
        GEMV64(p2, hbuf[L - 1][wr][2], wx_, 0.f);
        GEMV64(p3, hbuf[L - 1][wr][3], wx_, 0.f);
        // serial chain: h_L[t] = tanh(P_L[t] + Whh_L h_L[t-1] + bias)
        float hv;
        GEMV64(hv, hbuf[L][rd][3], wr_, bias);
        float h0v = fast_tanh(hv + p0); hbuf[L][wr][0][lane] = (__fp16)h0v;
        GEMV64(hv, hbuf[L][wr][0], wr_, bias);
        float h1v = fast_tanh(hv + p1); hbuf[L][wr][1][lane] = (__fp16)h1v;
        GEMV64(hv, hbuf[L][wr][1], wr_, bias);
        float h2v = fast_tanh(hv + p2); hbuf[L][wr][2][lane] = (__fp16)h2v;
        GEMV64(hv, hbuf[L][wr][2], wr_, bias);
        float h3v = fast_tanh(hv + p3); hbuf[L][wr][3][lane] = (__fp16)h3v;
      } else {
        // FC: out[t] = Wfc h3[t] + bfc, 4 independent
        float q0, q1, q2, q3;
        GEMV64(q0, hbuf[3][wr][0], wr_, bias);
        GEMV64(q1, hbuf[3][wr][1], wr_, bias);
        GEMV64(q2, hbuf[3][wr][2], wr_, bias);
        GEMV64(q3, hbuf[3][wr][3], wr_, bias);
        op[0]   = q0;
        op[64]  = q1;
        op[128] = q2;
        op[192] = q3;
        op += 256;
      }
    }
    // wave-4 x staging (by absolute k): window k+1 -> slot (k+1)&1, then
    // prefetch window k+2 into regs (one interval of latency cover)
    if (wv == 4 && k <= 254 && xact) {
      float4 xw = xr;
      if (k <= 253) xr = xg[(k + 2) * 52 + lane];
      pxs[(k + 1) & 1][xrow][2 * xcol]     = ubc(pk2(xw.x, xw.y));
      pxs[(k + 1) & 1][xrow][2 * xcol + 1] = ubc(pk2(xw.z, xw.w));
    }
    __syncthreads();  // uniform: every thread, every interval
  }
}

// ---------------------------------------------------------------------------
extern "C" void kernel_launch(void* const* d_in, const int* in_sizes, int n_in,
                              void* d_out, int out_size, void* d_ws,
                              size_t ws_size, hipStream_t stream) {
  const float* x    = (const float*)d_in[0];
  const float* Wih0 = (const float*)d_in[1];
  const float* Whh0 = (const float*)d_in[2];
  const float* bih0 = (const float*)d_in[3];
  const float* bhh0 = (const float*)d_in[4];
  const float* Wih  = (const float*)d_in[5];
  const float* Whh  = (const float*)d_in[6];
  const float* bih  = (const float*)d_in[7];
  const float* bhh  = (const float*)d_in[8];
  const float* Wfc  = (const float*)d_in[9];
  const float* bfc  = (const float*)d_in[10];
  float* out = (float*)d_out;

  const int B = in_sizes[0] / (T_STEPS * 52);  // 512
  (void)d_ws; (void)ws_size;                   // no workspace needed

  rnn_fused5<<<B, 320, 0, stream>>>(x, Wih0, bih0, bhh0, Whh0, Wih, Whh, bih,
                                    bhh, Wfc, bfc, out);
}